// Round 13
// baseline (107.997 us; speedup 1.0000x reference)
//
#include <hip/hip_runtime.h>
#include <hip/hip_bf16.h>

// B=32, IN_N=8192, POSE=64, M=8, NH=32, S2=256, HID=256, OUT_N=64
//
//  S[b,r][e]   = sum_{p<64} (CP[b, p*128+r] @ WC[p*128+r])[e],  r in [0,128), e=m1*8+m2
//              -> MFMA 16x16x32, 2 r's per wave (diag blocks), p half-split.
//              Stream loop: explicit 2-deep software pipeline, 8 WCf frags preloaded.
//  F[r,e,q]    = sum_{hh<4} E_proj[r>>2, (r&3)*64+e, hh*64+q]
//  pooled[b,q] = (1/64) sum_j S[b,j] * F[j,q]
//     fused pool -> P[b][32 slots][64]; LAST-ARRIVER block per b (mod-32 atomic
//     election, start-value invariant -> no counter reset needed) does the final
//     reduction + epilogue. 2 graph nodes total (prep, bc).
//  out[b,o,m1,m2] = sum_k (pooled[b,m1*8+k]+rel[m1*8+k]) * w_next[o,k,m2]

typedef short short8_t __attribute__((ext_vector_type(8)));
typedef float f32x4_t __attribute__((ext_vector_type(4)));
typedef int   int4_t  __attribute__((ext_vector_type(4)));

__device__ __forceinline__ short f2bf(float f) {
    union { float f; unsigned u; } v; v.f = f;
    unsigned r = v.u + 0x7FFFu + ((v.u >> 16) & 1u);   // RNE
    return (short)(r >> 16);
}

// packed f32x2 -> bf16x2 via HW instruction (no builtin on gfx950; m240)
__device__ __forceinline__ int cvt_pk(float x, float y) {
    int r;
    asm("v_cvt_pk_bf16_f32 %0, %1, %2" : "=v"(r) : "v"(x), "v"(y));
    return r;
}

// ---------- Kernel PREP: fused {WCf pack, E-fold} (identical since R6) ----------
__global__ void k_prep(const float* __restrict__ WC, short* __restrict__ WCf,
                       const float* __restrict__ E, float* __restrict__ F) {
    if (blockIdx.x < 256) {
        int t   = blockIdx.x * 256 + threadIdx.x;  // [0, 65536)
        int l   = t & 63;
        int pc  = (t >> 6) & 15;
        int rp  = t >> 10;
        int lhi = l >> 4;
        int j   = l & 15;
        int row = (pc * 4 + lhi) * 128 + rp * 2 + (j >> 3);
        const float* src = WC + ((size_t)row << 6) + (j & 7);
        short8_t o;
        #pragma unroll
        for (int k = 0; k < 8; ++k) o[k] = f2bf(src[k * 8]);
        ((short8_t*)WCf)[t] = o;
    } else {
        int idx = ((blockIdx.x - 256) * 256 + threadIdx.x) * 4;  // [0, 524288)
        int q   = idx & 63;
        int row = idx >> 6;
        int r   = row >> 6;
        int e   = row & 63;
        int nh  = r >> 2;
        int s2  = ((r & 3) << 6) + e;
        const float* base = E + (((size_t)nh * 256 + s2) << 8) + q;
        float4 s0 = *(const float4*)(base);
        float4 s1 = *(const float4*)(base + 64);
        float4 s2v = *(const float4*)(base + 128);
        float4 s3 = *(const float4*)(base + 192);
        float4 o;
        o.x = s0.x + s1.x + s2v.x + s3.x;
        o.y = s0.y + s1.y + s2v.y + s3.y;
        o.z = s0.z + s1.z + s2v.z + s3.z;
        o.w = s0.w + s1.w + s2v.w + s3.w;
        *(float4*)(F + idx) = o;
    }
}

// ---------- Kernel BC: pipelined stream + MFMA + fused pool + elected final ----------
// grid (32, 16): gx = rpg*2+half, gy = bq (b0 = bq*2). 512 threads = 8 waves.
__global__ void __launch_bounds__(512, 4)
k_bc(const float* __restrict__ CP, const short* __restrict__ WCf,
     const float* __restrict__ F, const float* __restrict__ rel,
     const float* __restrict__ WN, float* __restrict__ P,
     unsigned* __restrict__ cnt, float* __restrict__ out) {
    int gx   = blockIdx.x;
    int half = gx & 1;
    int rpg  = gx >> 1;              // [0,16)
    int b0   = blockIdx.y * 2;
    int w = threadIdx.x >> 6;        // [0,8)
    int l = threadIdx.x & 63;
    int b_loc  = w & 1;
    int rp_loc = w >> 1;             // [0,4)
    int rp = rpg * 4 + rp_loc;       // [0,64)
    int r0 = rp * 2;
    int b  = b0 + b_loc;

    int i16   = l & 15;
    int r_sel = i16 >> 3;
    int m1    = i16 & 7;
    int lhi   = l >> 4;              // [0,4)

    __shared__ float Stile[2][512];  // [b_loc][j_loc]
    __shared__ float redp[8][2][64]; // [wave][b_loc][q]
    __shared__ int   winflag[2];

    const float* cp_base = CP + ((size_t)b << 19) + ((size_t)(r0 + r_sel) << 6) + m1 * 8;
    const short8_t* wf   = (const short8_t*)WCf + (size_t)rp * 1024 + (half * 8) * 64 + l;

    // Pre-load ALL 8 B-fragments into registers
    short8_t wr0 = wf[0 * 64], wr1 = wf[1 * 64], wr2 = wf[2 * 64], wr3 = wf[3 * 64];
    short8_t wr4 = wf[4 * 64], wr5 = wf[5 * 64], wr6 = wf[6 * 64], wr7 = wf[7 * 64];

    const float* pbase = cp_base + (((size_t)(half * 8) * 4 + lhi) << 13);
    #define CPA(c) (pbase + ((size_t)((c) * 4) << 13))

    float4 a0A, a1A, b0A, b1A;
    float4 a0B, a1B, b0B, b1B;
    float4 a0C, a1C, b0C, b1C;
    float4 a0D, a1D, b0D, b1D;

    a0A = *(const float4*)(CPA(0));     a1A = *(const float4*)(CPA(0) + 4);
    b0A = *(const float4*)(CPA(1));     b1A = *(const float4*)(CPA(1) + 4);
    a0B = *(const float4*)(CPA(2));     a1B = *(const float4*)(CPA(2) + 4);
    b0B = *(const float4*)(CPA(3));     b1B = *(const float4*)(CPA(3) + 4);

    f32x4_t acc0 = {0.f, 0.f, 0.f, 0.f};
    f32x4_t acc1 = {0.f, 0.f, 0.f, 0.f};

    #define DO_PAIR(x0, x1, y0, y1, wlo, whi)                                  \
    {                                                                          \
        int4_t ai, bi;                                                         \
        ai[0] = cvt_pk(x0.x, x0.y); ai[1] = cvt_pk(x0.z, x0.w);                \
        ai[2] = cvt_pk(x1.x, x1.y); ai[3] = cvt_pk(x1.z, x1.w);                \
        bi[0] = cvt_pk(y0.x, y0.y); bi[1] = cvt_pk(y0.z, y0.w);                \
        bi[2] = cvt_pk(y1.x, y1.y); bi[3] = cvt_pk(y1.z, y1.w);                \
        acc0 = __builtin_amdgcn_mfma_f32_16x16x32_bf16(                        \
            __builtin_bit_cast(short8_t, ai), wlo, acc0, 0, 0, 0);             \
        acc1 = __builtin_amdgcn_mfma_f32_16x16x32_bf16(                        \
            __builtin_bit_cast(short8_t, bi), whi, acc1, 0, 0, 0);             \
    }

    a0C = *(const float4*)(CPA(4));     a1C = *(const float4*)(CPA(4) + 4);
    b0C = *(const float4*)(CPA(5));     b1C = *(const float4*)(CPA(5) + 4);
    DO_PAIR(a0A, a1A, b0A, b1A, wr0, wr1);
    a0D = *(const float4*)(CPA(6));     a1D = *(const float4*)(CPA(6) + 4);
    b0D = *(const float4*)(CPA(7));     b1D = *(const float4*)(CPA(7) + 4);
    DO_PAIR(a0B, a1B, b0B, b1B, wr2, wr3);
    DO_PAIR(a0C, a1C, b0C, b1C, wr4, wr5);
    DO_PAIR(a0D, a1D, b0D, b1D, wr6, wr7);
    #undef DO_PAIR
    #undef CPA

    f32x4_t acc;
    #pragma unroll
    for (int v = 0; v < 4; ++v) acc[v] = acc0[v] + acc1[v];

    // C/D layout (m89-verified): col = lane&15, row = (lane>>4)*4 + reg
    int col = i16;
    #pragma unroll
    for (int v = 0; v < 4; ++v) {
        int row = lhi * 4 + v;
        if (row < 8 && col < 8)
            Stile[b_loc][rp_loc * 128 + row * 8 + col] = acc[v];
        else if (row >= 8 && col >= 8)
            Stile[b_loc][rp_loc * 128 + 64 + (row - 8) * 8 + (col - 8)] = acc[v];
    }
    __syncthreads();

    // Pool phase: wave w covers jl in [w*64, w*64+64); F row read once, both b's.
    int g  = l >> 4;
    int ql = l & 15;
    const float* Fb = F + (((size_t)(rpg * 512 + w * 64 + g)) << 6) + ql * 4;
    f32x4_t p0 = {0.f, 0.f, 0.f, 0.f};
    f32x4_t p1 = {0.f, 0.f, 0.f, 0.f};
    #pragma unroll 4
    for (int s = 0; s < 16; ++s) {
        int jl = w * 64 + s * 4 + g;
        float4 fv = *(const float4*)(Fb + ((size_t)(s * 4) << 6));
        float s0 = Stile[0][jl];
        float s1 = Stile[1][jl];
        p0[0] += s0 * fv.x; p0[1] += s0 * fv.y; p0[2] += s0 * fv.z; p0[3] += s0 * fv.w;
        p1[0] += s1 * fv.x; p1[1] += s1 * fv.y; p1[2] += s1 * fv.z; p1[3] += s1 * fv.w;
    }
    #pragma unroll
    for (int c = 0; c < 4; ++c) {
        p0[c] += __shfl_xor(p0[c], 16, 64);
        p0[c] += __shfl_xor(p0[c], 32, 64);
        p1[c] += __shfl_xor(p1[c], 16, 64);
        p1[c] += __shfl_xor(p1[c], 32, 64);
    }
    if (l < 16) {
        *(f32x4_t*)(&redp[w][0][ql * 4]) = p0;
        *(f32x4_t*)(&redp[w][1][ql * 4]) = p1;
    }
    __syncthreads();

    // Cross-wave reduction -> P slot (b, gx)
    if (threadIdx.x < 128) {
        int bb = threadIdx.x >> 6;
        int q  = threadIdx.x & 63;
        float s = 0.f;
        #pragma unroll
        for (int ww = 0; ww < 8; ++ww) s += redp[ww][bb][q];
        P[((size_t)((b0 + bb) * 32 + gx) << 6) + q] = s;
    }

    // ---- Last-arriver election (no reset needed: mod-32 boundary crossing is
    //      invariant to the counters' initial value; 32 adds per b per launch) ----
    __threadfence();
    __syncthreads();
    if (threadIdx.x == 0) {
        unsigned o0 = __hip_atomic_fetch_add(&cnt[(size_t)(b0 + 0) << 4], 1u,
                                             __ATOMIC_ACQ_REL, __HIP_MEMORY_SCOPE_AGENT);
        unsigned o1 = __hip_atomic_fetch_add(&cnt[(size_t)(b0 + 1) << 4], 1u,
                                             __ATOMIC_ACQ_REL, __HIP_MEMORY_SCOPE_AGENT);
        winflag[0] = ((o0 + 1u) & 31u) == 0u;
        winflag[1] = ((o1 + 1u) & 31u) == 0u;
    }
    __syncthreads();

    #pragma unroll
    for (int bb = 0; bb < 2; ++bb) {
        if (!winflag[bb]) continue;          // block-uniform branch (LDS flag)
        int b_ = b0 + bb;
        int q = threadIdx.x & 63, sg = threadIdx.x >> 6;   // 8 groups x 4 slots
        const float* Pb = P + ((size_t)(b_ * 32) << 6);
        float s = 0.f;
        #pragma unroll
        for (int c = sg * 4; c < sg * 4 + 4; ++c)
            s += Pb[((size_t)c << 6) + q];
        redp[sg][0][q] = s;
        __syncthreads();
        if (threadIdx.x < 64) {
            float ss = 0.f;
            #pragma unroll
            for (int gg = 0; gg < 8; ++gg) ss += redp[gg][0][threadIdx.x];
            Stile[0][threadIdx.x] = ss * (1.0f / 64.0f) + rel[threadIdx.x];
        }
        __syncthreads();
        for (int idx = threadIdx.x; idx < 4096; idx += 512) {
            int o = idx >> 6, e = idx & 63, mm1 = e >> 3, mm2 = e & 7;
            float a = 0.f;
            #pragma unroll
            for (int k = 0; k < 8; ++k)
                a += Stile[0][mm1 * 8 + k] * WN[o * 64 + k * 8 + mm2];
            out[((size_t)b_ << 12) + idx] = a;
        }
        __syncthreads();
    }
}

extern "C" void kernel_launch(void* const* d_in, const int* in_sizes, int n_in,
                              void* d_out, int out_size, void* d_ws, size_t ws_size,
                              hipStream_t stream) {
    const float* current_pose = (const float*)d_in[0];  // (32, 8192, 64)
    const float* w_current    = (const float*)d_in[1];  // (1,1,8192,8,8)
    const float* w_next       = (const float*)d_in[2];  // (64,8,8)
    const float* E_proj       = (const float*)d_in[3];  // (32,256,256)
    const float* rel_embedd   = (const float*)d_in[4];  // (1,1,64)
    float* out = (float*)d_out;                         // (32,1,64,64)

    char* ws = (char*)d_ws;
    float*    F   = (float*)(ws);                            // 2 MiB
    short*    WCf = (short*)(ws + (2u << 20));               // 1 MiB
    float*    P   = (float*)(ws + (3u << 20));               // 256 KiB (32 x 32 x 64)
    unsigned* cnt = (unsigned*)(ws + (3u << 20) + (1u << 19)); // 32 counters, 64B apart

    // PREP: WCf pack (256 blocks) + E fold (512 blocks)
    k_prep<<<dim3(768), dim3(256), 0, stream>>>(w_current, WCf, E_proj, F);
    // BC: pipelined stream + MFMA + fused pool + elected final (2 nodes total)
    k_bc<<<dim3(32, 16), dim3(512), 0, stream>>>(current_pose, WCf, F, rel_embedd,
                                                 w_next, P, cnt, out);
}

// Round 14
// 48.549 us; speedup vs baseline: 2.2245x; 2.2245x over previous
//
#include <hip/hip_runtime.h>
#include <hip/hip_bf16.h>

// B=32, IN_N=8192, POSE=64, M=8, NH=32, S2=256, HID=256, OUT_N=64
//
//  S[b,r][e]   = sum_{p<64} (CP[b, p*128+r] @ WC[p*128+r])[e],  r in [0,128), e=m1*8+m2
//              -> MFMA 16x16x32, 2 r's per wave (diag blocks), p half-split.
//              smat = R12's stream code EXACTLY, minus the fused pool: writes
//              S halves as bf16 (1 MB total) coalesced. (Ablation: pool out of bc.)
//  F[r,e,q]    = sum_{hh<4} E_proj[r>>2, (r&3)*64+e, hh*64+q]   (bf16 now)
//  k_pf: block b stages Ssum[8192] in LDS (sums both halves), dots F once
//        (stride-32 j interleave: LDS conflict-free, F reads 512B/wave contiguous),
//        reduces, + rel, epilogue GEMM vs w_next. No P buffer, no 4th node.
//  out[b,o,m1,m2] = sum_k (pooled[b,m1*8+k]+rel[m1*8+k]) * w_next[o,k,m2]

typedef short short8_t __attribute__((ext_vector_type(8)));
typedef short short4_t __attribute__((ext_vector_type(4)));
typedef float f32x4_t __attribute__((ext_vector_type(4)));
typedef int   int4_t  __attribute__((ext_vector_type(4)));

__device__ __forceinline__ short f2bf(float f) {
    union { float f; unsigned u; } v; v.f = f;
    unsigned r = v.u + 0x7FFFu + ((v.u >> 16) & 1u);   // RNE
    return (short)(r >> 16);
}

// packed f32x2 -> bf16x2 via HW instruction (no builtin on gfx950; m240)
__device__ __forceinline__ int cvt_pk(float x, float y) {
    int r;
    asm("v_cvt_pk_bf16_f32 %0, %1, %2" : "=v"(r) : "v"(x), "v"(y));
    return r;
}

__device__ __forceinline__ float bf2f(unsigned short u) {
    union { float f; unsigned u; } v; v.u = ((unsigned)u) << 16; return v.f;
}

// ---------- Kernel PREP: WCf pack (blocks 0..255) + E-fold -> F16 bf16 ----------
__global__ void k_prep(const float* __restrict__ WC, short* __restrict__ WCf,
                       const float* __restrict__ E, short* __restrict__ F16) {
    if (blockIdx.x < 256) {
        int t   = blockIdx.x * 256 + threadIdx.x;  // [0, 65536)
        int l   = t & 63;
        int pc  = (t >> 6) & 15;
        int rp  = t >> 10;
        int lhi = l >> 4;
        int j   = l & 15;
        int row = (pc * 4 + lhi) * 128 + rp * 2 + (j >> 3);
        const float* src = WC + ((size_t)row << 6) + (j & 7);
        short8_t o;
        #pragma unroll
        for (int k = 0; k < 8; ++k) o[k] = f2bf(src[k * 8]);
        ((short8_t*)WCf)[t] = o;
    } else {
        int idx = ((blockIdx.x - 256) * 256 + threadIdx.x) * 4;  // [0, 524288)
        int q   = idx & 63;
        int row = idx >> 6;
        int r   = row >> 6;
        int e   = row & 63;
        int nh  = r >> 2;
        int s2  = ((r & 3) << 6) + e;
        const float* base = E + (((size_t)nh * 256 + s2) << 8) + q;
        float4 s0 = *(const float4*)(base);
        float4 s1 = *(const float4*)(base + 64);
        float4 s2v = *(const float4*)(base + 128);
        float4 s3 = *(const float4*)(base + 192);
        int2 u;
        u.x = cvt_pk(s0.x + s1.x + s2v.x + s3.x, s0.y + s1.y + s2v.y + s3.y);
        u.y = cvt_pk(s0.z + s1.z + s2v.z + s3.z, s0.w + s1.w + s2v.w + s3.w);
        *(int2*)(F16 + idx) = u;
    }
}

// ---------- Kernel SMAT: R12's pipelined stream+MFMA, S halves -> bf16 ----------
// grid (32, 16): gx = rpg*2+half, gy = bq (b0 = bq*2). 512 threads = 8 waves.
__global__ void __launch_bounds__(512, 4)
k_smat(const float* __restrict__ CP, const short* __restrict__ WCf,
       short* __restrict__ Sh) {
    int gx   = blockIdx.x;
    int half = gx & 1;
    int rpg  = gx >> 1;              // [0,16)
    int b0   = blockIdx.y * 2;
    int w = threadIdx.x >> 6;        // [0,8)
    int l = threadIdx.x & 63;
    int b_loc  = w & 1;
    int rp_loc = w >> 1;             // [0,4)
    int rp = rpg * 4 + rp_loc;       // [0,64)
    int r0 = rp * 2;
    int b  = b0 + b_loc;

    int i16   = l & 15;
    int r_sel = i16 >> 3;
    int m1    = i16 & 7;
    int lhi   = l >> 4;              // [0,4)

    __shared__ float Stile[2][512];  // [b_loc][j_loc]

    const float* cp_base = CP + ((size_t)b << 19) + ((size_t)(r0 + r_sel) << 6) + m1 * 8;
    const short8_t* wf   = (const short8_t*)WCf + (size_t)rp * 1024 + (half * 8) * 64 + l;

    short8_t wr0 = wf[0 * 64], wr1 = wf[1 * 64], wr2 = wf[2 * 64], wr3 = wf[3 * 64];
    short8_t wr4 = wf[4 * 64], wr5 = wf[5 * 64], wr6 = wf[6 * 64], wr7 = wf[7 * 64];

    const float* pbase = cp_base + (((size_t)(half * 8) * 4 + lhi) << 13);
    #define CPA(c) (pbase + ((size_t)((c) * 4) << 13))

    float4 a0A, a1A, b0A, b1A;
    float4 a0B, a1B, b0B, b1B;
    float4 a0C, a1C, b0C, b1C;
    float4 a0D, a1D, b0D, b1D;

    a0A = *(const float4*)(CPA(0));     a1A = *(const float4*)(CPA(0) + 4);
    b0A = *(const float4*)(CPA(1));     b1A = *(const float4*)(CPA(1) + 4);
    a0B = *(const float4*)(CPA(2));     a1B = *(const float4*)(CPA(2) + 4);
    b0B = *(const float4*)(CPA(3));     b1B = *(const float4*)(CPA(3) + 4);

    f32x4_t acc0 = {0.f, 0.f, 0.f, 0.f};
    f32x4_t acc1 = {0.f, 0.f, 0.f, 0.f};

    #define DO_PAIR(x0, x1, y0, y1, wlo, whi)                                  \
    {                                                                          \
        int4_t ai, bi;                                                         \
        ai[0] = cvt_pk(x0.x, x0.y); ai[1] = cvt_pk(x0.z, x0.w);                \
        ai[2] = cvt_pk(x1.x, x1.y); ai[3] = cvt_pk(x1.z, x1.w);                \
        bi[0] = cvt_pk(y0.x, y0.y); bi[1] = cvt_pk(y0.z, y0.w);                \
        bi[2] = cvt_pk(y1.x, y1.y); bi[3] = cvt_pk(y1.z, y1.w);                \
        acc0 = __builtin_amdgcn_mfma_f32_16x16x32_bf16(                        \
            __builtin_bit_cast(short8_t, ai), wlo, acc0, 0, 0, 0);             \
        acc1 = __builtin_amdgcn_mfma_f32_16x16x32_bf16(                        \
            __builtin_bit_cast(short8_t, bi), whi, acc1, 0, 0, 0);             \
    }

    a0C = *(const float4*)(CPA(4));     a1C = *(const float4*)(CPA(4) + 4);
    b0C = *(const float4*)(CPA(5));     b1C = *(const float4*)(CPA(5) + 4);
    DO_PAIR(a0A, a1A, b0A, b1A, wr0, wr1);
    a0D = *(const float4*)(CPA(6));     a1D = *(const float4*)(CPA(6) + 4);
    b0D = *(const float4*)(CPA(7));     b1D = *(const float4*)(CPA(7) + 4);
    DO_PAIR(a0B, a1B, b0B, b1B, wr2, wr3);
    DO_PAIR(a0C, a1C, b0C, b1C, wr4, wr5);
    DO_PAIR(a0D, a1D, b0D, b1D, wr6, wr7);
    #undef DO_PAIR
    #undef CPA

    f32x4_t acc;
    #pragma unroll
    for (int v = 0; v < 4; ++v) acc[v] = acc0[v] + acc1[v];

    // C/D layout (m89-verified): col = lane&15, row = (lane>>4)*4 + reg
    int col = i16;
    #pragma unroll
    for (int v = 0; v < 4; ++v) {
        int row = lhi * 4 + v;
        if (row < 8 && col < 8)
            Stile[b_loc][rp_loc * 128 + row * 8 + col] = acc[v];
        else if (row >= 8 && col >= 8)
            Stile[b_loc][rp_loc * 128 + 64 + (row - 8) * 8 + (col - 8)] = acc[v];
    }
    __syncthreads();

    // Coalesced bf16 write of the block's S slice: Sh[half*32 + b][rpg*512 + jl]
    {
        int tt  = threadIdx.x;
        int bl  = tt >> 8;               // [0,2)
        int jl0 = (tt & 255) * 2;
        int u = cvt_pk(Stile[bl][jl0], Stile[bl][jl0 + 1]);
        *(int*)(Sh + (((size_t)(half * 32 + b0 + bl)) << 13) + rpg * 512 + jl0) = u;
    }
}

// ---------- Kernel PF: pool (F read once per b) + finalize, one block per b ----------
__global__ void __launch_bounds__(512)
k_pf(const short* __restrict__ Sh, const short* __restrict__ F16,
     const float* __restrict__ rel, const float* __restrict__ WN,
     float* __restrict__ out) {
    int b = blockIdx.x;
    int t = threadIdx.x;

    __shared__ float Ssum[8192];     // 32 KB
    __shared__ float red2[32][64];   // 8 KB
    __shared__ float pool_s[64];

    // Stage: Ssum[j] = half0 + half1 (bf16 -> fp32), coalesced short8 loads
    {
        int j0 = t * 16;
        #pragma unroll
        for (int h = 0; h < 2; ++h) {
            int j = j0 + h * 8;
            short8_t v0 = *(const short8_t*)(Sh + ((size_t)(b) << 13) + j);
            short8_t v1 = *(const short8_t*)(Sh + ((size_t)(32 + b) << 13) + j);
            #pragma unroll
            for (int k = 0; k < 8; ++k)
                Ssum[j + k] = bf2f((unsigned short)v0[k]) + bf2f((unsigned short)v1[k]);
        }
    }
    __syncthreads();

    // Dot: thread (ql = t&15, jg = t>>4); j = s*32 + jg (LDS conflict-free,
    // F reads 512B contiguous per wave per iter)
    int ql = t & 15;
    int jg = t >> 4;                 // [0,32)
    f32x4_t acc = {0.f, 0.f, 0.f, 0.f};
    const short* Fb = F16 + ql * 4;
    #pragma unroll 8
    for (int s = 0; s < 256; ++s) {
        int j = s * 32 + jg;
        float sv = Ssum[j];
        short4_t fv = *(const short4_t*)(Fb + ((size_t)j << 6));
        acc[0] += sv * bf2f((unsigned short)fv[0]);
        acc[1] += sv * bf2f((unsigned short)fv[1]);
        acc[2] += sv * bf2f((unsigned short)fv[2]);
        acc[3] += sv * bf2f((unsigned short)fv[3]);
    }
    *(f32x4_t*)(&red2[jg][ql * 4]) = acc;
    __syncthreads();

    if (t < 64) {
        float s = 0.f;
        #pragma unroll
        for (int g = 0; g < 32; ++g) s += red2[g][t];
        pool_s[t] = s * (1.0f / 64.0f) + rel[t];
    }
    __syncthreads();

    for (int idx = t; idx < 4096; idx += 512) {
        int o = idx >> 6, e = idx & 63, m1 = e >> 3, m2 = e & 7;
        float a = 0.f;
        #pragma unroll
        for (int k = 0; k < 8; ++k)
            a += pool_s[m1 * 8 + k] * WN[o * 64 + k * 8 + m2];
        out[((size_t)b << 12) + idx] = a;
    }
}

extern "C" void kernel_launch(void* const* d_in, const int* in_sizes, int n_in,
                              void* d_out, int out_size, void* d_ws, size_t ws_size,
                              hipStream_t stream) {
    const float* current_pose = (const float*)d_in[0];  // (32, 8192, 64)
    const float* w_current    = (const float*)d_in[1];  // (1,1,8192,8,8)
    const float* w_next       = (const float*)d_in[2];  // (64,8,8)
    const float* E_proj       = (const float*)d_in[3];  // (32,256,256)
    const float* rel_embedd   = (const float*)d_in[4];  // (1,1,64)
    float* out = (float*)d_out;                         // (32,1,64,64)

    char* ws = (char*)d_ws;
    short* F16 = (short*)(ws);                    // 1 MiB (8192 x 64 bf16)
    short* WCf = (short*)(ws + (1u << 20));       // 1 MiB
    short* Sh  = (short*)(ws + (2u << 20));       // 1 MiB (2 halves x 32 x 8192 bf16)

    // PREP: WCf pack (256 blocks) + E fold -> bf16 F (512 blocks)
    k_prep<<<dim3(768), dim3(256), 0, stream>>>(w_current, WCf, E_proj, F16);
    // SMAT: pure stream + MFMA (R12 code minus pool), S halves bf16
    k_smat<<<dim3(32, 16), dim3(512), 0, stream>>>(current_pose, WCf, Sh);
    // PF: pool + finalize (F read once per b, 32 blocks)
    k_pf<<<dim3(32), dim3(512), 0, stream>>>(Sh, F16, rel_embedd, w_next, out);
}

// Round 15
// 27.785 us; speedup vs baseline: 3.8868x; 1.7473x over previous
//
#include <hip/hip_runtime.h>
#include <hip/hip_bf16.h>

// B=32, IN_N=8192, POSE=64, M=8, NH=32, S2=256, HID=256, OUT_N=64
//
//  S[b,r][e]   = sum_{p<64} (CP[b, p*128+r] @ WC[p*128+r])[e],  r in [0,128), e=m1*8+m2
//              -> MFMA 16x16x32, 2 r's per wave (diag blocks), p half-split.
//              Stream: global_load_lds (DMA, un-sinkable by compiler) into per-wave
//              private LDS double-buffer, paced by counted vmcnt(4) (never 0 mid-loop).
//  F[r,e,q]    = sum_{hh<4} E_proj[r>>2, (r&3)*64+e, hh*64+q]
//  pooled[b,q] = (1/64) sum_j S[b,j] * F[j,q]   (fused pool, identical to R12)
//  out[b,o,m1,m2] = sum_k (pooled[b,m1*8+k]+rel[m1*8+k]) * w_next[o,k,m2]

typedef short short8_t __attribute__((ext_vector_type(8)));
typedef float f32x4_t __attribute__((ext_vector_type(4)));
typedef int   int4_t  __attribute__((ext_vector_type(4)));

__device__ __forceinline__ short f2bf(float f) {
    union { float f; unsigned u; } v; v.f = f;
    unsigned r = v.u + 0x7FFFu + ((v.u >> 16) & 1u);   // RNE
    return (short)(r >> 16);
}

// packed f32x2 -> bf16x2 via HW instruction (no builtin on gfx950; m240)
__device__ __forceinline__ int cvt_pk(float x, float y) {
    int r;
    asm("v_cvt_pk_bf16_f32 %0, %1, %2" : "=v"(r) : "v"(x), "v"(y));
    return r;
}

// ---------- Kernel PREP: fused {WCf pack, E-fold} (identical since R6) ----------
__global__ void k_prep(const float* __restrict__ WC, short* __restrict__ WCf,
                       const float* __restrict__ E, float* __restrict__ F) {
    if (blockIdx.x < 256) {
        int t   = blockIdx.x * 256 + threadIdx.x;  // [0, 65536)
        int l   = t & 63;
        int pc  = (t >> 6) & 15;
        int rp  = t >> 10;
        int lhi = l >> 4;
        int j   = l & 15;
        int row = (pc * 4 + lhi) * 128 + rp * 2 + (j >> 3);
        const float* src = WC + ((size_t)row << 6) + (j & 7);
        short8_t o;
        #pragma unroll
        for (int k = 0; k < 8; ++k) o[k] = f2bf(src[k * 8]);
        ((short8_t*)WCf)[t] = o;
    } else {
        int idx = ((blockIdx.x - 256) * 256 + threadIdx.x) * 4;  // [0, 524288)
        int q   = idx & 63;
        int row = idx >> 6;
        int r   = row >> 6;
        int e   = row & 63;
        int nh  = r >> 2;
        int s2  = ((r & 3) << 6) + e;
        const float* base = E + (((size_t)nh * 256 + s2) << 8) + q;
        float4 s0 = *(const float4*)(base);
        float4 s1 = *(const float4*)(base + 64);
        float4 s2v = *(const float4*)(base + 128);
        float4 s3 = *(const float4*)(base + 192);
        float4 o;
        o.x = s0.x + s1.x + s2v.x + s3.x;
        o.y = s0.y + s1.y + s2v.y + s3.y;
        o.z = s0.z + s1.z + s2v.z + s3.z;
        o.w = s0.w + s1.w + s2v.w + s3.w;
        *(float4*)(F + idx) = o;
    }
}

// ---------- Kernel BC: gll-staged stream + MFMA + fused pool (pool == R12) ----------
// grid (32, 16): gx = rpg*2+half, gy = bq (b0 = bq*2). 512 threads = 8 waves.
__global__ void __launch_bounds__(512, 4)
k_bc(const float* __restrict__ CP, const short* __restrict__ WCf,
     const float* __restrict__ F, float* __restrict__ P) {
    int gx   = blockIdx.x;
    int half = gx & 1;
    int rpg  = gx >> 1;              // [0,16)
    int b0   = blockIdx.y * 2;
    int w = threadIdx.x >> 6;        // [0,8)
    int l = threadIdx.x & 63;
    int b_loc  = w & 1;
    int rp_loc = w >> 1;             // [0,4)
    int rp = rpg * 4 + rp_loc;       // [0,64)
    int r0 = rp * 2;
    int b  = b0 + b_loc;

    int i16   = l & 15;
    int r_sel = i16 >> 3;
    int m1    = i16 & 7;
    int lhi   = l >> 4;              // [0,4)

    __shared__ float gbuf[8][2048];  // 64 KB: per-wave private staging (2 bufs x 2 chunks)
    __shared__ float Stile[2][512];  // [b_loc][j_loc]
    __shared__ float redp[8][2][64]; // [wave][b_loc][q]

    const float* cp_base = CP + ((size_t)b << 19) + ((size_t)(r0 + r_sel) << 6) + m1 * 8;
    const short8_t* wf   = (const short8_t*)WCf + (size_t)rp * 1024 + (half * 8) * 64 + l;

    // Preload ALL 8 B-fragments and force materialization BEFORE gll issues,
    // so their implicit waitcnts cannot drain the gll pipeline later.
    short8_t wr0 = wf[0 * 64], wr1 = wf[1 * 64], wr2 = wf[2 * 64], wr3 = wf[3 * 64];
    short8_t wr4 = wf[4 * 64], wr5 = wf[5 * 64], wr6 = wf[6 * 64], wr7 = wf[7 * 64];
    asm volatile("" :: "v"(wr0), "v"(wr1), "v"(wr2), "v"(wr3),
                       "v"(wr4), "v"(wr5), "v"(wr6), "v"(wr7));
    asm volatile("s_waitcnt vmcnt(0)" ::: "memory");
    __builtin_amdgcn_sched_barrier(0);

    int wu = __builtin_amdgcn_readfirstlane(w);      // explicit wave-uniform
    float* gb = &gbuf[wu][0];

    const float* pbase = cp_base + (((size_t)(half * 8) * 4 + lhi) << 13);
    #define CPA(c) (pbase + ((size_t)((c) * 4) << 13))

    // DMA chunk c into floats [off, off+512): lane i's 16B lands at base + i*16.
    #define ISSUE(c, off) do {                                                        \
        __builtin_amdgcn_global_load_lds((const void*)(CPA(c)),                       \
                                         (void*)(gb + (off)), 16, 0, 0);              \
        __builtin_amdgcn_global_load_lds((const void*)(CPA(c) + 4),                   \
                                         (void*)(gb + (off) + 256), 16, 0, 0);        \
    } while (0)

    #define WAITVM(N) do {                                                            \
        asm volatile("s_waitcnt vmcnt(" #N ")" ::: "memory");                         \
        __builtin_amdgcn_sched_barrier(0);                                            \
    } while (0)

    f32x4_t acc0 = {0.f, 0.f, 0.f, 0.f};
    f32x4_t acc1 = {0.f, 0.f, 0.f, 0.f};

    #define COMPUTE(off, wfr, accX) do {                                              \
        float4 x0 = *(const float4*)(gb + (off) + (size_t)l * 4);                     \
        float4 x1 = *(const float4*)(gb + (off) + 256 + (size_t)l * 4);               \
        int4_t ai;                                                                    \
        ai[0] = cvt_pk(x0.x, x0.y); ai[1] = cvt_pk(x0.z, x0.w);                       \
        ai[2] = cvt_pk(x1.x, x1.y); ai[3] = cvt_pk(x1.z, x1.w);                       \
        accX = __builtin_amdgcn_mfma_f32_16x16x32_bf16(                               \
            __builtin_bit_cast(short8_t, ai), wfr, accX, 0, 0, 0);                    \
    } while (0)

    ISSUE(0, 0);    ISSUE(1, 512);      // buf0  (vm outstanding: 4)
    ISSUE(2, 1024); ISSUE(3, 1536);     // buf1  (8)
    WAITVM(4);                          // buf0 ready
    COMPUTE(0, wr0, acc0); COMPUTE(512, wr1, acc1);
    __builtin_amdgcn_sched_barrier(0);  // keep re-issue after the ds_reads above
    ISSUE(4, 0);    ISSUE(5, 512);      // refill buf0 (8)
    WAITVM(4);                          // buf1 ready
    COMPUTE(1024, wr2, acc0); COMPUTE(1536, wr3, acc1);
    __builtin_amdgcn_sched_barrier(0);
    ISSUE(6, 1024); ISSUE(7, 1536);     // refill buf1 (8)
    WAITVM(4);                          // buf0' ready
    COMPUTE(0, wr4, acc0); COMPUTE(512, wr5, acc1);
    WAITVM(0);                          // buf1' ready
    COMPUTE(1024, wr6, acc0); COMPUTE(1536, wr7, acc1);

    #undef COMPUTE
    #undef WAITVM
    #undef ISSUE
    #undef CPA

    f32x4_t acc;
    #pragma unroll
    for (int v = 0; v < 4; ++v) acc[v] = acc0[v] + acc1[v];

    // C/D layout (m89-verified): col = lane&15, row = (lane>>4)*4 + reg
    int col = i16;
    #pragma unroll
    for (int v = 0; v < 4; ++v) {
        int row = lhi * 4 + v;
        if (row < 8 && col < 8)
            Stile[b_loc][rp_loc * 128 + row * 8 + col] = acc[v];
        else if (row >= 8 && col >= 8)
            Stile[b_loc][rp_loc * 128 + 64 + (row - 8) * 8 + (col - 8)] = acc[v];
    }
    __syncthreads();

    // Pool phase (identical to R12): wave w covers jl in [w*64, w*64+64).
    int g  = l >> 4;
    int ql = l & 15;
    const float* Fb = F + (((size_t)(rpg * 512 + w * 64 + g)) << 6) + ql * 4;
    f32x4_t p0 = {0.f, 0.f, 0.f, 0.f};
    f32x4_t p1 = {0.f, 0.f, 0.f, 0.f};
    #pragma unroll 4
    for (int s = 0; s < 16; ++s) {
        int jl = w * 64 + s * 4 + g;
        float4 fv = *(const float4*)(Fb + ((size_t)(s * 4) << 6));
        float s0 = Stile[0][jl];
        float s1 = Stile[1][jl];
        p0[0] += s0 * fv.x; p0[1] += s0 * fv.y; p0[2] += s0 * fv.z; p0[3] += s0 * fv.w;
        p1[0] += s1 * fv.x; p1[1] += s1 * fv.y; p1[2] += s1 * fv.z; p1[3] += s1 * fv.w;
    }
    #pragma unroll
    for (int c = 0; c < 4; ++c) {
        p0[c] += __shfl_xor(p0[c], 16, 64);
        p0[c] += __shfl_xor(p0[c], 32, 64);
        p1[c] += __shfl_xor(p1[c], 16, 64);
        p1[c] += __shfl_xor(p1[c], 32, 64);
    }
    if (l < 16) {
        *(f32x4_t*)(&redp[w][0][ql * 4]) = p0;
        *(f32x4_t*)(&redp[w][1][ql * 4]) = p1;
    }
    __syncthreads();

    if (threadIdx.x < 128) {
        int bb = threadIdx.x >> 6;
        int q  = threadIdx.x & 63;
        float s = 0.f;
        #pragma unroll
        for (int ww = 0; ww < 8; ++ww) s += redp[ww][bb][q];
        P[((size_t)((b0 + bb) * 32 + gx) << 6) + q] = s;
    }
}

// ---------- Kernel FINAL (identical to R12) ----------
__global__ void k_final(const float* __restrict__ P, const float* __restrict__ rel,
                        const float* __restrict__ WN, float* __restrict__ out) {
    int b  = blockIdx.x;
    int t  = threadIdx.x;
    int q    = t & 63;
    int sgrp = t >> 6;               // [0,4): 8 slots each
    const float* Pb = P + ((size_t)(b * 32) << 6);
    float s = 0.f;
    #pragma unroll
    for (int c = sgrp * 8; c < sgrp * 8 + 8; ++c)
        s += Pb[((size_t)c << 6) + q];
    __shared__ float red[4][64];
    red[sgrp][q] = s;
    __syncthreads();
    __shared__ float pool_s[64];
    if (t < 64) {
        pool_s[t] = (red[0][t] + red[1][t] + red[2][t] + red[3][t]) * (1.0f / 64.0f)
                    + rel[t];
    }
    __syncthreads();
    #pragma unroll
    for (int idx = t; idx < 4096; idx += 256) {
        int o = idx >> 6;
        int e = idx & 63;
        int m1 = e >> 3, m2 = e & 7;
        float a = 0.f;
        #pragma unroll
        for (int k = 0; k < 8; ++k)
            a += pool_s[m1 * 8 + k] * WN[o * 64 + k * 8 + m2];
        out[((size_t)b << 12) + idx] = a;
    }
}

extern "C" void kernel_launch(void* const* d_in, const int* in_sizes, int n_in,
                              void* d_out, int out_size, void* d_ws, size_t ws_size,
                              hipStream_t stream) {
    const float* current_pose = (const float*)d_in[0];  // (32, 8192, 64)
    const float* w_current    = (const float*)d_in[1];  // (1,1,8192,8,8)
    const float* w_next       = (const float*)d_in[2];  // (64,8,8)
    const float* E_proj       = (const float*)d_in[3];  // (32,256,256)
    const float* rel_embedd   = (const float*)d_in[4];  // (1,1,64)
    float* out = (float*)d_out;                         // (32,1,64,64)

    char* ws = (char*)d_ws;
    float* F   = (float*)(ws);                    // 2 MiB
    short* WCf = (short*)(ws + (2u << 20));       // 1 MiB
    float* P   = (float*)(ws + (3u << 20));       // 256 KiB (32 x 32 x 64)

    // PREP: WCf pack (256 blocks) + E fold (512 blocks)
    k_prep<<<dim3(768), dim3(256), 0, stream>>>(w_current, WCf, E_proj, F);
    // BC: gll-staged stream + MFMA + fused pool
    k_bc<<<dim3(32, 16), dim3(512), 0, stream>>>(current_pose, WCf, F, P);
    // FINAL
    k_final<<<dim3(32), dim3(256), 0, stream>>>(P, rel_embedd, w_next, out);
}